// Round 10
// baseline (416.800 us; speedup 1.0000x reference)
//
#include <hip/hip_runtime.h>
#include <hip/hip_bf16.h>

// Problem constants (fixed by reference)
#define T_TOTAL 786432
#define N_IN 50
#define K_FEAT 400
#define C_OUT 10
#define NSEG 32768                  // T/24 pooled segments

// ---- workspace layout ----
// [0,      51200)  : w1f   — W1 16x16 MFMA B-frags (fallback kernel)
// [51200,  83200)  : w2t   — W2 transposed floats (fallback epilogue)
// [98304,  151552) : w1f32 — W1 32x32 MFMA B-frags: frag fi=(ft*4+kt)*64+lane, 8 shorts
// [163840, 190464) : w2p   — W2 per-lane f32 blob for fused epilogue:
//                            w2p[(ft*64+lane)*8 + c] = W2[(lane>>5)*5+c][32*ft+(lane&31)]
#define W1F_TASKS (25 * 2 * 64)        // 3200
#define W2T_OFF_BYTES 51200
#define W2T_FLOATS (25 * 320)          // 8000
#define W1F32_OFF_BYTES 98304
#define W1F32_TASKS (13 * 4 * 64)      // 3328
#define W2P_OFF_BYTES 163840
#define W2P_TASKS (13 * 64)            // 832, each writes 8 floats
#define PREP_TASKS (W1F_TASKS + W2T_FLOATS + W1F32_TASKS + W2P_TASKS)
#define WS_NEEDED (W2P_OFF_BYTES + (size_t)W2P_TASKS * 8 * 4)

typedef __bf16 bfx8 __attribute__((ext_vector_type(8)));
typedef short  s16x8 __attribute__((ext_vector_type(8)));
typedef float  f32x2 __attribute__((ext_vector_type(2)));
typedef float  f32x4 __attribute__((ext_vector_type(4)));
typedef float  f32x16 __attribute__((ext_vector_type(16)));

static __device__ __forceinline__ short f2bf(float f) {
    union { float f; unsigned u; } v; v.f = f;
    unsigned r = v.u + 0x7fffu + ((v.u >> 16) & 1u);
    return (short)(r >> 16);
}

// ================= prep: build fragment-ordered weight blobs =================
__global__ void prep_kernel(const float* __restrict__ W1,
                            const float* __restrict__ W2,
                            short* __restrict__ w1f, float* __restrict__ w2t,
                            short* __restrict__ w1f32, float* __restrict__ w2p)
{
    const int gid = blockIdx.x * blockDim.x + threadIdx.x;
    if (gid < W1F_TASKS) {
        const int lane = gid & 63;
        const int s    = (gid >> 6) & 1;
        const int tile = gid >> 7;          // 0..24
        const int m16  = lane & 15;
        const int quad = lane >> 4;
        const float* row = W1 + (tile * 16 + m16) * N_IN;
        s16x8 v;
        #pragma unroll
        for (int j = 0; j < 8; ++j) {
            const int n = s * 32 + quad * 8 + j;
            v[j] = (n < N_IN) ? f2bf(row[n]) : (short)0;
        }
        *(s16x8*)&w1f[gid * 8] = v;
    } else if (gid < W1F_TASKS + W2T_FLOATS) {
        const int i   = gid - W1F_TASKS;    // i = j*320 + tid
        const int j   = i / 320;
        const int tid = i - j * 320;
        const int o    = tid >> 4;
        const int part = tid & 15;
        const int seg  = (o >= 10) ? 1 : 0;
        const int cls  = o - seg * 10;
        w2t[i] = W2[cls * K_FEAT + part * 25 + j];
    } else if (gid < W1F_TASKS + W2T_FLOATS + W1F32_TASKS) {
        // w1f32: B-frag for 32x32x16 GEMM1. B[k][n]: lane l holds
        // B[k=(l>>5)*8+j][n=l&31] = W1[feat=ft*32+(l&31)][col=kt*16+(l>>5)*8+j]
        const int i    = gid - W1F_TASKS - W2T_FLOATS;   // (ft*4+kt)*64+lane
        const int lane = i & 63;
        const int fi   = i >> 6;            // 0..51
        const int ft   = fi >> 2;           // 0..12
        const int kt   = fi & 3;            // 0..3
        const int feat = ft * 32 + (lane & 31);
        const int cbase = kt * 16 + (lane >> 5) * 8;
        s16x8 v;
        #pragma unroll
        for (int j = 0; j < 8; ++j) {
            const int col = cbase + j;
            v[j] = (feat < K_FEAT && col < N_IN) ? f2bf(W1[feat * N_IN + col])
                                                 : (short)0;
        }
        *(s16x8*)&w1f32[i * 8] = v;
    } else if (gid < PREP_TASKS) {
        // w2p: per-lane f32 W2 slice for the fused epilogue.
        // lane (h=l>>5, m32=l&31) handles classes h*5..h*5+4, feat = 32*ft+m32.
        const int i    = gid - W1F_TASKS - W2T_FLOATS - W1F32_TASKS; // ft*64+lane
        const int lane = i & 63;
        const int ft   = i >> 6;            // 0..12
        const int m32  = lane & 31;
        const int h    = lane >> 5;
        const int feat = 32 * ft + m32;
        float v[8];
        #pragma unroll
        for (int c = 0; c < 8; ++c)
            v[c] = (c < 5 && feat < K_FEAT) ? W2[(h * 5 + c) * K_FEAT + feat]
                                            : 0.f;
        float4* dst = (float4*)&w2p[(size_t)i * 8];
        dst[0] = make_float4(v[0], v[1], v[2], v[3]);
        dst[1] = make_float4(v[4], v[5], v[6], v[7]);
    }
}

// ==== fused phase 1: coalesced x->LDS, GEMM1(32x32x16)+relu+pool+W2, 1 pass ====
// wave = one 96-row chunk = 4 pooling segments. 2048 blocks x 4 waves = 8192.
// LDS: per-wave 96x50 bf16 slab, linear (row stride 100 B -> bank step 25,
// coprime with 32 => conflict-free frag reads). 38.4 KB/block.
// Round-10: DISTANCE-2 B PREFETCH on the round-3 champion (94 us). Evidence:
// distance-1 dbuf (r3, 94) vs single-buffer (r6/7/8, 97-100) shows B-load
// latency partially exposed at depth 1; round 9 showed tripling load events
// regresses 26 us -> B latency IS the residual stall. Three B register sets,
// 4 rolled iters x 3 inlined bodies: no rotation copies (also deletes r3's
// 16 Bc=Bn movs/ft), each B loaded ~2 bodies (~800 cyc) before use. Body is
// byte-identical to round 3 (zacc, packed pool, shfl_xor(32) combine,
// h-split w2p-8 epilogue, setprio). (256,3) = 170-reg budget, est ~100.
// Tripwires: WRITE_SIZE <= ~3.3 MB, VGPR ~100-115.
__global__ __launch_bounds__(256, 3) void phase1_kernel(
    const float* __restrict__ x, const short* __restrict__ w1f32,
    const float* __restrict__ w2p, float* __restrict__ out)
{
    __shared__ __align__(16) short xs[4 * 4800];
    const int tid  = threadIdx.x;
    const int lane = tid & 63;
    const int wv   = tid >> 6;
    const int m32  = lane & 31;
    const int h    = lane >> 5;
    const int chunk = blockIdx.x * 4 + wv;   // 0..8191
    short* myxs = xs + wv * 4800;
    const s16x8* wf = (const s16x8*)w1f32;

    auto loadB = [&](s16x8* B, int ft) {
        #pragma unroll
        for (int kt = 0; kt < 4; ++kt) B[kt] = wf[(ft * 4 + kt) * 64 + lane];
    };

    // ---- prefetch ft=0/1 weights BEFORE staging (arrive under x stream) ----
    s16x8 B0[4], B1[4], B2[4];
    loadB(B0, 0);
    loadB(B1, 1);

    // ---- stage 96x50 f32 -> bf16 LDS, fully coalesced (float4 per lane) ----
    {
        const float* xg = x + (size_t)chunk * 4800;
        #pragma unroll
        for (int i = 0; i < 19; ++i) {
            const int q = 64 * i + lane;            // float4 index, 1200 total
            if (i < 18 || lane < 48) {
                const float4 v = *(const float4*)(xg + 4 * q);
                int lo, hi;
                asm("v_cvt_pk_bf16_f32 %0, %1, %2" : "=v"(lo) : "v"(v.x), "v"(v.y));
                asm("v_cvt_pk_bf16_f32 %0, %1, %2" : "=v"(hi) : "v"(v.z), "v"(v.w));
                int2 pk; pk.x = lo; pk.y = hi;
                *(int2*)&myxs[4 * q] = pk;          // ds_write_b64, linear
            }
        }
    }
    loadB(B2, 2);       // third pipeline stage, still ahead of first use
    // wave-private LDS region: no barrier needed, just drain our ds_writes
    asm volatile("s_waitcnt lgkmcnt(0)" ::: "memory");
    __builtin_amdgcn_sched_barrier(0);

    // ---- build A fragments from LDS (bank-conflict-free b32 reads) ----
    // A[m=l&31][k=(l>>5)*8+j]; k = kt*16 + 8h + j
    s16x8 Af[3][4];
    #pragma unroll
    for (int rt = 0; rt < 3; ++rt) {
        const int row = 32 * rt + m32;
        const short* rp = myxs + row * 50 + 8 * h;
        #pragma unroll
        for (int kt = 0; kt < 3; ++kt) {
            int d0 = *(const int*)(rp + 16 * kt + 0);
            int d1 = *(const int*)(rp + 16 * kt + 2);
            int d2 = *(const int*)(rp + 16 * kt + 4);
            int d3 = *(const int*)(rp + 16 * kt + 6);
            int4 di = {d0, d1, d2, d3};
            Af[rt][kt] = __builtin_bit_cast(s16x8, di);
        }
        // kt=3: only cols 48,49 exist (h==0, j=0,1); rest must be exact zero
        int dt = 0;
        if (h == 0) dt = *(const int*)(myxs + row * 50 + 48);
        int4 di3 = {dt, 0, 0, 0};
        Af[rt][3] = __builtin_bit_cast(s16x8, di3);
    }

    const int segbase = chunk * 4;

    float oacc[4][5];
    #pragma unroll
    for (int s = 0; s < 4; ++s)
        #pragma unroll
        for (int c = 0; c < 5; ++c) oacc[s][c] = 0.f;

    // hoisted zero accumulator: loop-invariant C operand for the first MFMA
    // of each chain (round-3 proven at the (256,3) budget)
    f32x16 zacc;
    #pragma unroll
    for (int r = 0; r < 16; ++r) zacc[r] = 0.f;
    const f32x2 z2 = {0.f, 0.f};

    // ---- per-ft body: byte-identical arithmetic to round 3 ----
    auto ft_body = [&](int ft, const s16x8* B) {
        // w2 slice for THIS ft, issued before the MFMAs so latency hides
        const float* wl = w2p + (size_t)(ft * 64 + lane) * 8;
        const float4 wa = *(const float4*)wl;
        const float  w4 = wl[4];

        float s0 = 0.f, s1 = 0.f, s2 = 0.f, s3 = 0.f;
        #pragma unroll
        for (int rt = 0; rt < 3; ++rt) {
            __builtin_amdgcn_s_setprio(1);
            f32x16 acc = __builtin_amdgcn_mfma_f32_32x32x16_bf16(
                        __builtin_bit_cast(bfx8, Af[rt][0]),
                        __builtin_bit_cast(bfx8, B[0]), zacc, 0, 0, 0);
            #pragma unroll
            for (int kt = 1; kt < 4; ++kt)
                acc = __builtin_amdgcn_mfma_f32_32x32x16_bf16(
                        __builtin_bit_cast(bfx8, Af[rt][kt]),
                        __builtin_bit_cast(bfx8, B[kt]), acc, 0, 0, 0);
            __builtin_amdgcn_s_setprio(0);
            // C/D: row = (reg&3) + 8*(reg>>2) + 4h + 32rt; col = m32.
            // Segment boundary (24|48|72) falls between reg-groups:
            // rt=0: regs 0..11 -> seg0, 12..15 -> seg1
            // rt=1: regs 0..7  -> seg1, 8..15  -> seg2
            // rt=2: regs 0..3  -> seg2, 4..15  -> seg3   (uniform in h, m32)
            f32x2 cv0 = z2, cv1 = z2;
            #pragma unroll
            for (int p = 0; p < 8; ++p) {
                f32x2 v2; v2[0] = acc[2 * p]; v2[1] = acc[2 * p + 1];
                v2 = __builtin_elementwise_max(v2, z2);
                if ((p >> 1) < 3 - rt) cv0 += v2; else cv1 += v2;
            }
            const float c0 = cv0[0] + cv0[1];
            const float c1 = cv1[0] + cv1[1];
            if (rt == 0)      { s0 += c0; s1 += c1; }
            else if (rt == 1) { s1 += c0; s2 += c1; }
            else              { s2 += c0; s3 += c1; }
        }
        // combine the two half-waves (h=0/1 hold interleaved rows)
        s0 += __shfl_xor(s0, 32);
        s1 += __shfl_xor(s1, 32);
        s2 += __shfl_xor(s2, 32);
        s3 += __shfl_xor(s3, 32);

        // fused second GEMM: oacc[seg][c] += s_seg * W2[h*5+c][32*ft+m32]
        const float wc[5] = {wa.x, wa.y, wa.z, wa.w, w4};
        const float sv[4] = {s0, s1, s2, s3};
        #pragma unroll
        for (int s = 0; s < 4; ++s)
            #pragma unroll
            for (int c = 0; c < 5; ++c)
                oacc[s][c] = fmaf(sv[s], wc[c], oacc[s][c]);
    };

    // ---- 3-stage software pipeline over ft = 0..12 (rolled x4, no copies) ----
    for (int ftb = 0; ftb < 12; ftb += 3) {
        ft_body(ftb, B0);
        if (ftb + 3 <= 12) loadB(B0, ftb + 3);
        ft_body(ftb + 1, B1);
        if (ftb + 4 <= 12) loadB(B1, ftb + 4);
        ft_body(ftb + 2, B2);
        if (ftb + 5 <= 12) loadB(B2, ftb + 5);
    }
    ft_body(12, B0);

    // ---- reduce feat-partials across the 32 lanes of each half-wave ----
    // (strides 1..16 stay within each 32-lane half)
    float red[4][5];
    #pragma unroll
    for (int s = 0; s < 4; ++s)
        #pragma unroll
        for (int c = 0; c < 5; ++c) {
            float v = oacc[s][c];
            v += __shfl_xor(v, 1);
            v += __shfl_xor(v, 2);
            v += __shfl_xor(v, 4);
            v += __shfl_xor(v, 8);
            v += __shfl_xor(v, 16);
            red[s][c] = v;
        }
    if (m32 == 0) {
        #pragma unroll
        for (int s = 0; s < 4; ++s)
            #pragma unroll
            for (int c = 0; c < 5; ++c)
                out[(size_t)(segbase + s) * C_OUT + h * 5 + c] =
                    red[s][c] * (1.0f / 24.0f);
    }
}

// ================= fallback (round-3 fused kernel, verbatim) ================
#define FB_CPB 4
#define FB_NTHREADS 320
#define FB_XS_STRIDE 72
#define FB_XS_ROWS (FB_CPB * 48)

__global__ __launch_bounds__(FB_NTHREADS) void classifier_fb(
    const float* __restrict__ x, const short* __restrict__ w1f,
    const float* __restrict__ w2t, float* __restrict__ out)
{
    __shared__ short xs[FB_XS_ROWS * FB_XS_STRIDE];
    __shared__ float pooled[2 * K_FEAT];

    const int tid  = threadIdx.x;
    const int wave = tid >> 6;
    const int lane = tid & 63;
    const int m16  = lane & 15;
    const int quad = lane >> 4;

    {
        const float* xb = x + (size_t)blockIdx.x * (FB_XS_ROWS * N_IN);
        #pragma unroll
        for (int it = 0; it < (FB_XS_ROWS * 25) / FB_NTHREADS; ++it) {
            const int i = tid + it * FB_NTHREADS;
            const int r = i / 25;
            const int c2 = i - r * 25;
            const float2 v = *(const float2*)(xb + 2 * i);
            const int packed = (unsigned short)f2bf(v.x) |
                               ((unsigned)(unsigned short)f2bf(v.y) << 16);
            *(int*)&xs[r * FB_XS_STRIDE + 2 * c2] = packed;
        }
        for (int i = tid; i < FB_XS_ROWS * 7; i += FB_NTHREADS) {
            const int r = i / 7;
            const int c = 50 + 2 * (i - r * 7);
            *(int*)&xs[r * FB_XS_STRIDE + c] = 0;
        }
    }

    s16x8 bfrag[5][2];
    {
        const s16x8* wf = (const s16x8*)w1f;
        #pragma unroll
        for (int t = 0; t < 5; ++t)
            #pragma unroll
            for (int s = 0; s < 2; ++s)
                bfrag[t][s] = wf[((wave * 5 + t) * 2 + s) * 64 + lane];
    }

    const int o    = tid >> 4;
    const int part = tid & 15;
    const int segO = (o >= 10) ? 1 : 0;
    const int cls  = o - segO * 10;
    float w2r[25];
    #pragma unroll
    for (int j = 0; j < 25; ++j) w2r[j] = w2t[j * FB_NTHREADS + tid];

    __syncthreads();

    for (int ciq = 0; ciq < FB_CPB; ++ciq) {
        s16x8 a[3][2];
        #pragma unroll
        for (int r = 0; r < 3; ++r) {
            const short* arow =
                &xs[(ciq * 48 + r * 16 + m16) * FB_XS_STRIDE + quad * 8];
            a[r][0] = *(const s16x8*)(arow);
            a[r][1] = *(const s16x8*)(arow + 32);
        }
        #pragma unroll
        for (int t = 0; t < 5; ++t) {
            float c0 = 0.f, c1 = 0.f;
            #pragma unroll
            for (int r = 0; r < 3; ++r) {
                f32x4 acc = {0.f, 0.f, 0.f, 0.f};
                acc = __builtin_amdgcn_mfma_f32_16x16x32_bf16(
                        __builtin_bit_cast(bfx8, a[r][0]),
                        __builtin_bit_cast(bfx8, bfrag[t][0]), acc, 0, 0, 0);
                acc = __builtin_amdgcn_mfma_f32_16x16x32_bf16(
                        __builtin_bit_cast(bfx8, a[r][1]),
                        __builtin_bit_cast(bfx8, bfrag[t][1]), acc, 0, 0, 0);
                const float s = fmaxf(acc[0], 0.f) + fmaxf(acc[1], 0.f)
                              + fmaxf(acc[2], 0.f) + fmaxf(acc[3], 0.f);
                if (r * 4 + quad < 6) c0 += s; else c1 += s;
            }
            c0 += __shfl_xor(c0, 16); c0 += __shfl_xor(c0, 32);
            c1 += __shfl_xor(c1, 16); c1 += __shfl_xor(c1, 32);
            if (quad == 0) {
                const int feat = (wave * 5 + t) * 16 + m16;
                pooled[feat] = c0;
                pooled[K_FEAT + feat] = c1;
            }
        }
        __syncthreads();

        float sum = 0.f;
        const float* pv = &pooled[segO * K_FEAT + part * 25];
        #pragma unroll
        for (int j = 0; j < 25; ++j) sum += pv[j] * w2r[j];
        sum += __shfl_down(sum, 8, 16);
        sum += __shfl_down(sum, 4, 16);
        sum += __shfl_down(sum, 2, 16);
        sum += __shfl_down(sum, 1, 16);
        if (part == 0) {
            const int chunk = blockIdx.x * FB_CPB + ciq;
            out[(chunk * 2 + segO) * C_OUT + cls] = sum * (1.0f / 24.0f);
        }
        __syncthreads();
    }
}

// ============================== launch ======================================
extern "C" void kernel_launch(void* const* d_in, const int* in_sizes, int n_in,
                              void* d_out, int out_size, void* d_ws, size_t ws_size,
                              hipStream_t stream) {
    const float* x  = (const float*)d_in[0];
    const float* W1 = (const float*)d_in[1];
    const float* W2 = (const float*)d_in[2];
    float* out = (float*)d_out;

    short* w1f   = (short*)d_ws;
    float* w2t   = (float*)((char*)d_ws + W2T_OFF_BYTES);
    short* w1f32 = (short*)((char*)d_ws + W1F32_OFF_BYTES);
    float* w2p   = (float*)((char*)d_ws + W2P_OFF_BYTES);

    prep_kernel<<<(PREP_TASKS + 255) / 256, 256, 0, stream>>>(W1, W2, w1f, w2t,
                                                              w1f32, w2p);

    if (ws_size >= WS_NEEDED) {
        phase1_kernel<<<2048, 256, 0, stream>>>(x, w1f32, w2p, out);
    } else {
        classifier_fb<<<4096, FB_NTHREADS, 0, stream>>>(x, w1f, w2t, out);
    }
}

// Round 11
// 250.047 us; speedup vs baseline: 1.6669x; 1.6669x over previous
//
#include <hip/hip_runtime.h>
#include <hip/hip_bf16.h>

// Problem constants (fixed by reference)
#define T_TOTAL 786432
#define N_IN 50
#define K_FEAT 400
#define C_OUT 10
#define NSEG 32768                  // T/24 pooled segments

// ---- workspace layout ----
// [0,      51200)  : w1f   — W1 16x16 MFMA B-frags (fallback kernel)
// [51200,  83200)  : w2t   — W2 transposed floats (fallback epilogue)
// [98304,  151552) : w1f32 — W1 32x32 MFMA B-frags: frag fi=(ft*4+kt)*64+lane, 8 shorts
// [163840, 190464) : w2p   — W2 per-lane f32 blob for fused epilogue:
//                            w2p[(ft*64+lane)*8 + c] = W2[(lane>>5)*5+c][32*ft+(lane&31)]
#define W1F_TASKS (25 * 2 * 64)        // 3200
#define W2T_OFF_BYTES 51200
#define W2T_FLOATS (25 * 320)          // 8000
#define W1F32_OFF_BYTES 98304
#define W1F32_TASKS (13 * 4 * 64)      // 3328
#define W2P_OFF_BYTES 163840
#define W2P_TASKS (13 * 64)            // 832, each writes 8 floats
#define PREP_TASKS (W1F_TASKS + W2T_FLOATS + W1F32_TASKS + W2P_TASKS)
#define WS_NEEDED (W2P_OFF_BYTES + (size_t)W2P_TASKS * 8 * 4)

typedef __bf16 bfx8 __attribute__((ext_vector_type(8)));
typedef short  s16x8 __attribute__((ext_vector_type(8)));
typedef float  f32x2 __attribute__((ext_vector_type(2)));
typedef float  f32x4 __attribute__((ext_vector_type(4)));
typedef float  f32x16 __attribute__((ext_vector_type(16)));

static __device__ __forceinline__ short f2bf(float f) {
    union { float f; unsigned u; } v; v.f = f;
    unsigned r = v.u + 0x7fffu + ((v.u >> 16) & 1u);
    return (short)(r >> 16);
}

// ================= prep: build fragment-ordered weight blobs =================
__global__ void prep_kernel(const float* __restrict__ W1,
                            const float* __restrict__ W2,
                            short* __restrict__ w1f, float* __restrict__ w2t,
                            short* __restrict__ w1f32, float* __restrict__ w2p)
{
    const int gid = blockIdx.x * blockDim.x + threadIdx.x;
    if (gid < W1F_TASKS) {
        const int lane = gid & 63;
        const int s    = (gid >> 6) & 1;
        const int tile = gid >> 7;          // 0..24
        const int m16  = lane & 15;
        const int quad = lane >> 4;
        const float* row = W1 + (tile * 16 + m16) * N_IN;
        s16x8 v;
        #pragma unroll
        for (int j = 0; j < 8; ++j) {
            const int n = s * 32 + quad * 8 + j;
            v[j] = (n < N_IN) ? f2bf(row[n]) : (short)0;
        }
        *(s16x8*)&w1f[gid * 8] = v;
    } else if (gid < W1F_TASKS + W2T_FLOATS) {
        const int i   = gid - W1F_TASKS;    // i = j*320 + tid
        const int j   = i / 320;
        const int tid = i - j * 320;
        const int o    = tid >> 4;
        const int part = tid & 15;
        const int seg  = (o >= 10) ? 1 : 0;
        const int cls  = o - seg * 10;
        w2t[i] = W2[cls * K_FEAT + part * 25 + j];
    } else if (gid < W1F_TASKS + W2T_FLOATS + W1F32_TASKS) {
        // w1f32: B-frag for 32x32x16 GEMM1. B[k][n]: lane l holds
        // B[k=(l>>5)*8+j][n=l&31] = W1[feat=ft*32+(l&31)][col=kt*16+(l>>5)*8+j]
        const int i    = gid - W1F_TASKS - W2T_FLOATS;   // (ft*4+kt)*64+lane
        const int lane = i & 63;
        const int fi   = i >> 6;            // 0..51
        const int ft   = fi >> 2;           // 0..12
        const int kt   = fi & 3;            // 0..3
        const int feat = ft * 32 + (lane & 31);
        const int cbase = kt * 16 + (lane >> 5) * 8;
        s16x8 v;
        #pragma unroll
        for (int j = 0; j < 8; ++j) {
            const int col = cbase + j;
            v[j] = (feat < K_FEAT && col < N_IN) ? f2bf(W1[feat * N_IN + col])
                                                 : (short)0;
        }
        *(s16x8*)&w1f32[i * 8] = v;
    } else if (gid < PREP_TASKS) {
        // w2p: per-lane f32 W2 slice for the fused epilogue.
        // lane (h=l>>5, m32=l&31) handles classes h*5..h*5+4, feat = 32*ft+m32.
        const int i    = gid - W1F_TASKS - W2T_FLOATS - W1F32_TASKS; // ft*64+lane
        const int lane = i & 63;
        const int ft   = i >> 6;            // 0..12
        const int m32  = lane & 31;
        const int h    = lane >> 5;
        const int feat = 32 * ft + m32;
        float v[8];
        #pragma unroll
        for (int c = 0; c < 8; ++c)
            v[c] = (c < 5 && feat < K_FEAT) ? W2[(h * 5 + c) * K_FEAT + feat]
                                            : 0.f;
        float4* dst = (float4*)&w2p[(size_t)i * 8];
        dst[0] = make_float4(v[0], v[1], v[2], v[3]);
        dst[1] = make_float4(v[4], v[5], v[6], v[7]);
    }
}

// ==== fused phase 1: coalesced x->LDS, GEMM1(32x32x16)+relu+pool+W2, 1 pass ====
// wave = one 96-row chunk = 4 pooling segments. 2048 blocks x 4 waves = 8192.
// LDS: per-wave 96x50 bf16 slab, linear (row stride 100 B -> bank step 25,
// coprime with 32 => conflict-free frag reads). 38.4 KB/block.
// __launch_bounds__(256,3): 170-reg budget -> no meaningful spill (VGPR 84).
// FINAL (round-11): round-3 champion, verbatim — best of 11 rounds (94 us
// phase1, 252 us e2e). Ledger of falsified alternatives: coalescing fix
// (r1-2 null), spill-free variants (r7/r8 null), shuffle-free deferred
// combine (r8 null), 4-block occupancy (r6/r7 null), rt-split concurrency
// (r9 -26%), distance-2 prefetch (r10 spill disaster). Distance-1 B dbuf
// (here) is the only pipelining depth that fits the register budget.
__global__ __launch_bounds__(256, 3) void phase1_kernel(
    const float* __restrict__ x, const short* __restrict__ w1f32,
    const float* __restrict__ w2p, float* __restrict__ out)
{
    __shared__ __align__(16) short xs[4 * 4800];
    const int tid  = threadIdx.x;
    const int lane = tid & 63;
    const int wv   = tid >> 6;
    const int m32  = lane & 31;
    const int h    = lane >> 5;
    const int chunk = blockIdx.x * 4 + wv;   // 0..8191
    short* myxs = xs + wv * 4800;
    const s16x8* wf = (const s16x8*)w1f32;

    // ---- prefetch ft=0 weights BEFORE staging: they arrive under the
    //      19-load x stream instead of stalling the first loop iteration ----
    s16x8 Bc[4], Bn[4];
    #pragma unroll
    for (int kt = 0; kt < 4; ++kt) Bc[kt] = wf[kt * 64 + lane];

    // ---- stage 96x50 f32 -> bf16 LDS, fully coalesced (float4 per lane) ----
    {
        const float* xg = x + (size_t)chunk * 4800;
        #pragma unroll
        for (int i = 0; i < 19; ++i) {
            const int q = 64 * i + lane;            // float4 index, 1200 total
            if (i < 18 || lane < 48) {
                const float4 v = *(const float4*)(xg + 4 * q);
                int lo, hi;
                asm("v_cvt_pk_bf16_f32 %0, %1, %2" : "=v"(lo) : "v"(v.x), "v"(v.y));
                asm("v_cvt_pk_bf16_f32 %0, %1, %2" : "=v"(hi) : "v"(v.z), "v"(v.w));
                int2 pk; pk.x = lo; pk.y = hi;
                *(int2*)&myxs[4 * q] = pk;          // ds_write_b64, linear
            }
        }
    }
    // wave-private LDS region: no barrier needed, just drain our ds_writes
    asm volatile("s_waitcnt lgkmcnt(0)" ::: "memory");
    __builtin_amdgcn_sched_barrier(0);

    // ---- build A fragments from LDS (bank-conflict-free b32 reads) ----
    // A[m=l&31][k=(l>>5)*8+j]; k = kt*16 + 8h + j
    s16x8 Af[3][4];
    #pragma unroll
    for (int rt = 0; rt < 3; ++rt) {
        const int row = 32 * rt + m32;
        const short* rp = myxs + row * 50 + 8 * h;
        #pragma unroll
        for (int kt = 0; kt < 3; ++kt) {
            int d0 = *(const int*)(rp + 16 * kt + 0);
            int d1 = *(const int*)(rp + 16 * kt + 2);
            int d2 = *(const int*)(rp + 16 * kt + 4);
            int d3 = *(const int*)(rp + 16 * kt + 6);
            int4 di = {d0, d1, d2, d3};
            Af[rt][kt] = __builtin_bit_cast(s16x8, di);
        }
        // kt=3: only cols 48,49 exist (h==0, j=0,1); rest must be exact zero
        int dt = 0;
        if (h == 0) dt = *(const int*)(myxs + row * 50 + 48);
        int4 di3 = {dt, 0, 0, 0};
        Af[rt][3] = __builtin_bit_cast(s16x8, di3);
    }

    const int segbase = chunk * 4;

    float oacc[4][5];
    #pragma unroll
    for (int s = 0; s < 4; ++s)
        #pragma unroll
        for (int c = 0; c < 5; ++c) oacc[s][c] = 0.f;

    // hoisted zero accumulator: loop-invariant C operand for the first MFMA
    // of each chain (kills 16 re-zero movs x 3 rt x 13 ft per wave)
    f32x16 zacc;
    #pragma unroll
    for (int r = 0; r < 16; ++r) zacc[r] = 0.f;
    const f32x2 z2 = {0.f, 0.f};

    // ---- ft-loop over 13 feature tiles (32 feats), B double-buffered ----
    for (int ft = 0; ft < 13; ++ft) {
        const int ftn = (ft < 12) ? ft + 1 : 12;
        #pragma unroll
        for (int kt = 0; kt < 4; ++kt) Bn[kt] = wf[(ftn * 4 + kt) * 64 + lane];
        // w2 slice for THIS ft, issued before the MFMAs so latency hides
        const float* wl = w2p + (size_t)(ft * 64 + lane) * 8;
        const float4 wa = *(const float4*)wl;
        const float  w4 = wl[4];

        float s0 = 0.f, s1 = 0.f, s2 = 0.f, s3 = 0.f;
        #pragma unroll
        for (int rt = 0; rt < 3; ++rt) {
            f32x16 acc = __builtin_amdgcn_mfma_f32_32x32x16_bf16(
                        __builtin_bit_cast(bfx8, Af[rt][0]),
                        __builtin_bit_cast(bfx8, Bc[0]), zacc, 0, 0, 0);
            #pragma unroll
            for (int kt = 1; kt < 4; ++kt)
                acc = __builtin_amdgcn_mfma_f32_32x32x16_bf16(
                        __builtin_bit_cast(bfx8, Af[rt][kt]),
                        __builtin_bit_cast(bfx8, Bc[kt]), acc, 0, 0, 0);
            // C/D: row = (reg&3) + 8*(reg>>2) + 4h + 32rt; col = m32.
            // Segment boundary (24|48|72) falls between reg-groups:
            // rt=0: regs 0..11 -> seg0, 12..15 -> seg1
            // rt=1: regs 0..7  -> seg1, 8..15  -> seg2
            // rt=2: regs 0..3  -> seg2, 4..15  -> seg3   (uniform in h, m32)
            // Packed-f32 pooling: pairs (2p,2p+1) never straddle a reg-group
            // boundary (groups are 4 regs), so relu+sum runs on v_pk_* ops.
            f32x2 cv0 = z2, cv1 = z2;
            #pragma unroll
            for (int p = 0; p < 8; ++p) {
                f32x2 v2; v2[0] = acc[2 * p]; v2[1] = acc[2 * p + 1];
                v2 = __builtin_elementwise_max(v2, z2);
                if ((p >> 1) < 3 - rt) cv0 += v2; else cv1 += v2;
            }
            const float c0 = cv0[0] + cv0[1];
            const float c1 = cv1[0] + cv1[1];
            if (rt == 0)      { s0 += c0; s1 += c1; }
            else if (rt == 1) { s1 += c0; s2 += c1; }
            else              { s2 += c0; s3 += c1; }
        }
        // combine the two half-waves (h=0/1 hold interleaved rows)
        s0 += __shfl_xor(s0, 32);
        s1 += __shfl_xor(s1, 32);
        s2 += __shfl_xor(s2, 32);
        s3 += __shfl_xor(s3, 32);

        // fused second GEMM: oacc[seg][c] += s_seg * W2[h*5+c][32*ft+m32]
        {
            const float wc[5] = {wa.x, wa.y, wa.z, wa.w, w4};
            const float sv[4] = {s0, s1, s2, s3};
            #pragma unroll
            for (int s = 0; s < 4; ++s)
                #pragma unroll
                for (int c = 0; c < 5; ++c)
                    oacc[s][c] = fmaf(sv[s], wc[c], oacc[s][c]);
        }
        #pragma unroll
        for (int kt = 0; kt < 4; ++kt) Bc[kt] = Bn[kt];
    }

    // ---- reduce feat-partials across the 32 lanes of each half-wave ----
    #pragma unroll
    for (int s = 0; s < 4; ++s)
        #pragma unroll
        for (int c = 0; c < 5; ++c) {
            float v = oacc[s][c];
            v += __shfl_xor(v, 1);
            v += __shfl_xor(v, 2);
            v += __shfl_xor(v, 4);
            v += __shfl_xor(v, 8);
            v += __shfl_xor(v, 16);
            oacc[s][c] = v;
        }
    if (m32 == 0) {
        #pragma unroll
        for (int s = 0; s < 4; ++s)
            #pragma unroll
            for (int c = 0; c < 5; ++c)
                out[(size_t)(segbase + s) * C_OUT + h * 5 + c] =
                    oacc[s][c] * (1.0f / 24.0f);
    }
}

// ================= fallback (round-3 fused kernel, verbatim) ================
#define FB_CPB 4
#define FB_NTHREADS 320
#define FB_XS_STRIDE 72
#define FB_XS_ROWS (FB_CPB * 48)

__global__ __launch_bounds__(FB_NTHREADS) void classifier_fb(
    const float* __restrict__ x, const short* __restrict__ w1f,
    const float* __restrict__ w2t, float* __restrict__ out)
{
    __shared__ short xs[FB_XS_ROWS * FB_XS_STRIDE];
    __shared__ float pooled[2 * K_FEAT];

    const int tid  = threadIdx.x;
    const int wave = tid >> 6;
    const int lane = tid & 63;
    const int m16  = lane & 15;
    const int quad = lane >> 4;

    {
        const float* xb = x + (size_t)blockIdx.x * (FB_XS_ROWS * N_IN);
        #pragma unroll
        for (int it = 0; it < (FB_XS_ROWS * 25) / FB_NTHREADS; ++it) {
            const int i = tid + it * FB_NTHREADS;
            const int r = i / 25;
            const int c2 = i - r * 25;
            const float2 v = *(const float2*)(xb + 2 * i);
            const int packed = (unsigned short)f2bf(v.x) |
                               ((unsigned)(unsigned short)f2bf(v.y) << 16);
            *(int*)&xs[r * FB_XS_STRIDE + 2 * c2] = packed;
        }
        for (int i = tid; i < FB_XS_ROWS * 7; i += FB_NTHREADS) {
            const int r = i / 7;
            const int c = 50 + 2 * (i - r * 7);
            *(int*)&xs[r * FB_XS_STRIDE + c] = 0;
        }
    }

    s16x8 bfrag[5][2];
    {
        const s16x8* wf = (const s16x8*)w1f;
        #pragma unroll
        for (int t = 0; t < 5; ++t)
            #pragma unroll
            for (int s = 0; s < 2; ++s)
                bfrag[t][s] = wf[((wave * 5 + t) * 2 + s) * 64 + lane];
    }

    const int o    = tid >> 4;
    const int part = tid & 15;
    const int segO = (o >= 10) ? 1 : 0;
    const int cls  = o - segO * 10;
    float w2r[25];
    #pragma unroll
    for (int j = 0; j < 25; ++j) w2r[j] = w2t[j * FB_NTHREADS + tid];

    __syncthreads();

    for (int ciq = 0; ciq < FB_CPB; ++ciq) {
        s16x8 a[3][2];
        #pragma unroll
        for (int r = 0; r < 3; ++r) {
            const short* arow =
                &xs[(ciq * 48 + r * 16 + m16) * FB_XS_STRIDE + quad * 8];
            a[r][0] = *(const s16x8*)(arow);
            a[r][1] = *(const s16x8*)(arow + 32);
        }
        #pragma unroll
        for (int t = 0; t < 5; ++t) {
            float c0 = 0.f, c1 = 0.f;
            #pragma unroll
            for (int r = 0; r < 3; ++r) {
                f32x4 acc = {0.f, 0.f, 0.f, 0.f};
                acc = __builtin_amdgcn_mfma_f32_16x16x32_bf16(
                        __builtin_bit_cast(bfx8, a[r][0]),
                        __builtin_bit_cast(bfx8, bfrag[t][0]), acc, 0, 0, 0);
                acc = __builtin_amdgcn_mfma_f32_16x16x32_bf16(
                        __builtin_bit_cast(bfx8, a[r][1]),
                        __builtin_bit_cast(bfx8, bfrag[t][1]), acc, 0, 0, 0);
                const float s = fmaxf(acc[0], 0.f) + fmaxf(acc[1], 0.f)
                              + fmaxf(acc[2], 0.f) + fmaxf(acc[3], 0.f);
                if (r * 4 + quad < 6) c0 += s; else c1 += s;
            }
            c0 += __shfl_xor(c0, 16); c0 += __shfl_xor(c0, 32);
            c1 += __shfl_xor(c1, 16); c1 += __shfl_xor(c1, 32);
            if (quad == 0) {
                const int feat = (wave * 5 + t) * 16 + m16;
                pooled[feat] = c0;
                pooled[K_FEAT + feat] = c1;
            }
        }
        __syncthreads();

        float sum = 0.f;
        const float* pv = &pooled[segO * K_FEAT + part * 25];
        #pragma unroll
        for (int j = 0; j < 25; ++j) sum += pv[j] * w2r[j];
        sum += __shfl_down(sum, 8, 16);
        sum += __shfl_down(sum, 4, 16);
        sum += __shfl_down(sum, 2, 16);
        sum += __shfl_down(sum, 1, 16);
        if (part == 0) {
            const int chunk = blockIdx.x * FB_CPB + ciq;
            out[(chunk * 2 + segO) * C_OUT + cls] = sum * (1.0f / 24.0f);
        }
        __syncthreads();
    }
}

// ============================== launch ======================================
extern "C" void kernel_launch(void* const* d_in, const int* in_sizes, int n_in,
                              void* d_out, int out_size, void* d_ws, size_t ws_size,
                              hipStream_t stream) {
    const float* x  = (const float*)d_in[0];
    const float* W1 = (const float*)d_in[1];
    const float* W2 = (const float*)d_in[2];
    float* out = (float*)d_out;

    short* w1f   = (short*)d_ws;
    float* w2t   = (float*)((char*)d_ws + W2T_OFF_BYTES);
    short* w1f32 = (short*)((char*)d_ws + W1F32_OFF_BYTES);
    float* w2p   = (float*)((char*)d_ws + W2P_OFF_BYTES);

    prep_kernel<<<(PREP_TASKS + 255) / 256, 256, 0, stream>>>(W1, W2, w1f, w2t,
                                                              w1f32, w2p);

    if (ws_size >= WS_NEEDED) {
        phase1_kernel<<<2048, 256, 0, stream>>>(x, w1f32, w2p, out);
    } else {
        classifier_fb<<<4096, FB_NTHREADS, 0, stream>>>(x, w1f, w2t, out);
    }
}